// Round 17
// baseline (420.272 us; speedup 1.0000x reference)
//
#include <hip/hip_runtime.h>

#define DD   256    // feature dim
#define CC   100    // num classes
#define TPB_ARG 192            // argmax: 3 waves
#define WAVES_ACC 16           // accum: 16 waves/block
#define ROWS_PER_WAVE 64       // contiguous run per wave
#define SLAB (WAVES_ACC * ROWS_PER_WAVE)   // 1024 rows per accum block

typedef float f4 __attribute__((ext_vector_type(4)));

// Workspace layout (bytes):
//   [0, 102400)        : g_sums   (CC*DD f32)
//   [102400, 102800)   : g_counts (CC int)
//   [102800, 102808)   : g_sumsq  (1 double)
//   [103424, +4N)      : cls      (N int)
#define WS_SUMS_OFF   0
#define WS_COUNTS_OFF (CC * DD * 4)
#define WS_SUMSQ_OFF  (WS_COUNTS_OFF + CC * 4)
#define WS_HDR        (WS_SUMSQ_OFF + 8)
#define WS_CLS_OFF    103424

// ---------------- kernel A: argmax via DMA-staged LDS tiles -----------------
// (r10 structure — proven ~15-20 µs) Wave-private 2x25.6KB LDS ping-pong,
// 25x global_load_lds w16 per 64-row tile, counted vmcnt, per-lane row argmax,
// cls[] store + LDS histogram -> g_counts.
__global__ __launch_bounds__(TPB_ARG) void k_argmax(
        const float* __restrict__ labels,
        int*   __restrict__ cls,
        int*   __restrict__ g_counts,
        int N)
{
    __shared__ f4  stage[3][2][1600];    // 3 waves x 2 bufs x 25600 B = 150 KB
    __shared__ int s_cnt[CC];

    const int tid  = threadIdx.x;
    const int lane = tid & 63;
    const int wid  = tid >> 6;
    if (tid < CC) s_cnt[tid] = 0;
    __syncthreads();

    const int ntiles = N >> 6;
    const int S      = gridDim.x * 3;    // total waves

#define DMA(b_, t_) do {                                                      \
    const float* gbase = labels + (size_t)(t_) * 6400 + lane * 4;             \
    f4* lbase = &stage[wid][b_][0];                                           \
    _Pragma("unroll")                                                         \
    for (int i_ = 0; i_ < 25; ++i_)                                           \
        __builtin_amdgcn_global_load_lds(                                     \
            (const __attribute__((address_space(1))) unsigned int*)(gbase + i_ * 256), \
            (__attribute__((address_space(3))) unsigned int*)(lbase + i_ * 64),       \
            16, 0, 0);                                                        \
} while (0)

#define CONSUME(b_, t_) do {                                                  \
    const f4* row_ = &stage[wid][b_][lane * 25];                              \
    f4 q0_ = row_[0];                                                         \
    float best_ = q0_[0]; int bi_ = 0;                                        \
    if (q0_[1] > best_) { best_ = q0_[1]; bi_ = 1; }                          \
    if (q0_[2] > best_) { best_ = q0_[2]; bi_ = 2; }                          \
    if (q0_[3] > best_) { best_ = q0_[3]; bi_ = 3; }                          \
    _Pragma("unroll")                                                         \
    for (int j_ = 1; j_ < 25; ++j_) {                                         \
        f4 q_ = row_[j_];                                                     \
        if (q_[0] > best_) { best_ = q_[0]; bi_ = 4 * j_; }                   \
        if (q_[1] > best_) { best_ = q_[1]; bi_ = 4 * j_ + 1; }               \
        if (q_[2] > best_) { best_ = q_[2]; bi_ = 4 * j_ + 2; }               \
        if (q_[3] > best_) { best_ = q_[3]; bi_ = 4 * j_ + 3; }               \
    }                                                                         \
    cls[(size_t)(t_) * 64 + lane] = bi_;                                      \
    atomicAdd(&s_cnt[bi_], 1);                                                \
} while (0)

    int t = blockIdx.x * 3 + wid;
    if (t < ntiles) {
        DMA(0, t);
        int cur = 0;
        int tn  = t + S;
        while (tn < ntiles) {
            DMA(cur ^ 1, tn);                         // prefetch next tile
            asm volatile("s_waitcnt vmcnt(25)" ::: "memory");  // cur tile ready
            __builtin_amdgcn_sched_barrier(0);
            CONSUME(cur, t);
            cur ^= 1; t = tn; tn += S;
        }
        asm volatile("s_waitcnt vmcnt(0)" ::: "memory");
        __builtin_amdgcn_sched_barrier(0);
        CONSUME(cur, t);
    }
#undef DMA
#undef CONSUME

    // tail rows (N % 64 != 0)
    if (blockIdx.x == 0 && wid == 0) {
        const int row = (ntiles << 6) + lane;
        if (row < N) {
            const float* lr = labels + (size_t)row * CC;
            float best = lr[0]; int bi = 0;
            for (int j = 1; j < CC; ++j)
                if (lr[j] > best) { best = lr[j]; bi = j; }
            cls[row] = bi;
            atomicAdd(&s_cnt[bi], 1);
        }
    }

    __syncthreads();
    if (tid < CC) {
        const int c = s_cnt[tid];
        if (c) atomicAdd(&g_counts[tid], c);
    }
}

// ---------------- kernel B: sequential DMA-streamed class-sum accumulate ----
// Each wave owns a CONTIGUOUS 64-row (64KB) run -> dense sequential DRAM
// streams (vs r16's random 1KB gathers at ~50% page efficiency). One
// global_load_lds instruction per full 1KB row into a wave-private 3-slot
// LDS ring; counted vmcnt(2) keeps 3KB/wave (48KB/CU) in flight — compiler
// can't serialize DMA. Consume: transposed LDS reads (bank=lane%32, free
// 2-way) + ds_add_f32 into the 100KB class-sum tile (same free pattern).
// cls: ONE coalesced load per wave, then readlane per row.
__global__ __launch_bounds__(SLAB) void k_accum(
        const float* __restrict__ feats,
        const int*   __restrict__ cls,
        float* __restrict__ g_sums,
        double* __restrict__ g_sumsq,
        int N)
{
    __shared__ float  s_sums[CC * DD];               // 100 KB
    __shared__ f4     stage[WAVES_ACC][3][64];       // 48 KB (3x1KB per wave)
    __shared__ double s_red[WAVES_ACC];

    const int tid  = threadIdx.x;
    const int lane = tid & 63;
    const int wid  = tid >> 6;

    for (int i = tid; i < CC * DD; i += SLAB) s_sums[i] = 0.f;
    __syncthreads();

    const int base = blockIdx.x * SLAB + wid * ROWS_PER_WAVE;

    // lane i holds cls of row base+i (one coalesced load per wave)
    const int crow = base + lane;
    const int ccls = cls[(crow < N) ? crow : (N - 1)];

#define DMA(buf_, i_) do {                                                    \
    int r_ = base + (i_);                                                     \
    if (r_ >= N) r_ = N - 1;                                                  \
    const float* g_ = feats + (size_t)r_ * DD + lane * 4;                     \
    __builtin_amdgcn_global_load_lds(                                         \
        (const __attribute__((address_space(1))) unsigned int*)g_,            \
        (__attribute__((address_space(3))) unsigned int*)&stage[wid][buf_][0],\
        16, 0, 0);                                                            \
} while (0)

    DMA(0, 0); DMA(1, 1); DMA(2, 2);                 // prologue: 3 in flight

    float ssq = 0.f;
    const float* const wbase = (const float*)&stage[wid][0][0];

    for (int i = 0; i < ROWS_PER_WAVE; ++i) {
        const int buf = i - (i / 3) * 3;             // i % 3
        asm volatile("s_waitcnt vmcnt(2)" ::: "memory");   // oldest row landed
        __builtin_amdgcn_sched_barrier(0);

        const int row = base + i;                    // wave-uniform guard
        if (row < N) {
            const int c = __builtin_amdgcn_readlane(ccls, i);  // SGPR class
            const float* sf = wbase + buf * 256;     // this row, linear layout
            const float v0 = sf[0 * 64 + lane];      // transposed read:
            const float v1 = sf[1 * 64 + lane];      // bank = lane%32 (free)
            const float v2 = sf[2 * 64 + lane];
            const float v3 = sf[3 * 64 + lane];
            ssq += v0 * v0 + v1 * v1 + v2 * v2 + v3 * v3;
            float* dst = &s_sums[c * DD + lane];     // bank = lane%32 (free)
            unsafeAtomicAdd(dst +   0, v0);          // ds_add_f32, no return
            unsafeAtomicAdd(dst +  64, v1);
            unsafeAtomicAdd(dst + 128, v2);
            unsafeAtomicAdd(dst + 192, v3);
        }
        // ds_reads of this buf are complete (register dep enforced above);
        // drain DS queue before the DMA that overwrites the slot.
        asm volatile("s_waitcnt lgkmcnt(0)" ::: "memory");
        __builtin_amdgcn_sched_barrier(0);
        DMA(buf, i + 3);                             // refill (clamped at tail)
    }
    asm volatile("s_waitcnt vmcnt(0) lgkmcnt(0)" ::: "memory");
    __builtin_amdgcn_sched_barrier(0);
#undef DMA

    // ---- sumsq: wave reduce -> block reduce -> one f64 atomic per block ----
    double ds = (double)ssq;
    #pragma unroll
    for (int off = 1; off < 64; off <<= 1) ds += __shfl_xor(ds, off);
    if (lane == 0) s_red[wid] = ds;
    __syncthreads();                                 // also: all ds_adds done
    if (tid == 0) {
        double t = 0.0;
        #pragma unroll
        for (int k = 0; k < WAVES_ACC; ++k) t += s_red[k];
        atomicAdd(g_sumsq, t);
    }

    // ---- flush class-sum tile: fire-and-forget global f32 atomics ----
    for (int i = tid; i < CC * DD; i += SLAB) {
        const float s = s_sums[i];
        if (s != 0.f) unsafeAtomicAdd(&g_sums[i], s);
    }
}

// ---------------- finalize (batched independent loads) ----------------------
__global__ __launch_bounds__(DD) void affinity_finalize(
        const float* __restrict__ g_sums,
        const int*   __restrict__ g_counts,
        const double* __restrict__ g_sumsq,
        float* __restrict__ out)
{
    const int d = threadIdx.x;
    __shared__ int s_cnt[CC];
    if (d < CC) s_cnt[d] = g_counts[d];
    __syncthreads();

    double colsum = 0.0, s2 = 0.0, dot = 0.0, cc = 0.0;
    for (int cb = 0; cb < CC; cb += 4) {             // CC % 4 == 0
        float s[4];
        #pragma unroll
        for (int k = 0; k < 4; ++k)                  // 4 independent loads
            s[k] = g_sums[(size_t)(cb + k) * DD + d];
        #pragma unroll
        for (int k = 0; k < 4; ++k) {
            const int    cnt = s_cnt[cb + k];
            const double center = (cnt > 0 ? (double)s[k] / (double)cnt : 0.0) + 1e-6;
            colsum += center;
            s2     += center * center;
            dot    += center * (double)s[k];
            cc     += (double)cnt * center * center;
        }
    }
    double interp = s2 - colsum * colsum / (double)CC;

    __shared__ double red0[DD], red1[DD], red2[DD];
    red0[d] = dot; red1[d] = cc; red2[d] = interp;
    __syncthreads();
    for (int off = DD / 2; off > 0; off >>= 1) {
        if (d < off) {
            red0[d] += red0[d + off];
            red1[d] += red1[d + off];
            red2[d] += red2[d + off];
        }
        __syncthreads();
    }
    if (d == 0) {
        const double intra = *g_sumsq - 2.0 * red0[0] + red1[0];
        const double inter = red2[0] / (double)CC;
        out[0] = (float)(intra / (inter + 1e-6));
    }
}

extern "C" void kernel_launch(void* const* d_in, const int* in_sizes, int n_in,
                              void* d_out, int out_size, void* d_ws, size_t ws_size,
                              hipStream_t stream)
{
    const float* feats  = (const float*)d_in[0];
    const float* labels = (const float*)d_in[1];
    const int N = in_sizes[0] / DD;

    float*  g_sums   = (float*)((char*)d_ws + WS_SUMS_OFF);
    int*    g_counts = (int*)((char*)d_ws + WS_COUNTS_OFF);
    double* g_sumsq  = (double*)((char*)d_ws + WS_SUMSQ_OFF);
    int*    cls      = (int*)((char*)d_ws + WS_CLS_OFF);

    hipMemsetAsync(d_ws, 0, WS_HDR, stream);     // zero sums/counts/sumsq

    k_argmax<<<256, TPB_ARG, 0, stream>>>(labels, cls, g_counts, N);

    const int nbB = (N + SLAB - 1) / SLAB;       // 256 for N=262144
    k_accum<<<nbB, SLAB, 0, stream>>>(feats, cls, g_sums, g_sumsq, N);

    affinity_finalize<<<1, DD, 0, stream>>>(g_sums, g_counts, g_sumsq,
                                            (float*)d_out);
}